// Round 13
// baseline (512.947 us; speedup 1.0000x reference)
//
#include <hip/hip_runtime.h>
#include <math.h>

constexpr int kN = 8192;
constexpr int kE = 131072;
constexpr int NPB = 16;   // nodes per gather block

typedef short bf16x8 __attribute__((ext_vector_type(8)));
typedef float f32x4 __attribute__((ext_vector_type(4)));
typedef unsigned short ushort_t;
typedef unsigned int uint_t;

__device__ __forceinline__ float silu_f(float x) { return x / (1.f + __expf(-x)); }

__device__ __forceinline__ ushort_t f2b(float f) {
  uint_t x = __float_as_uint(f);
  uint_t r = (x + 0x7fffu + ((x >> 16) & 1u)) >> 16;
  return (ushort_t)r;
}
__device__ __forceinline__ float b2f(ushort_t u) {
  return __uint_as_float(((uint_t)u) << 16);
}

__global__ __launch_bounds__(256) void zero_ints_kernel(int* __restrict__ a, int* __restrict__ b) {
  int i = blockIdx.x * 256 + threadIdx.x;
  if (i < kN) { a[i] = 0; b[i] = 0; }
}

__global__ __launch_bounds__(256) void elem_kernel(const float* __restrict__ attrs, int* __restrict__ elem) {
  int n = blockIdx.x * 256 + threadIdx.x;
  if (n >= kN) return;
  const float* a = attrs + (size_t)n * 10;
  int best = 0; float bv = a[0];
  #pragma unroll
  for (int z = 1; z < 10; ++z) { float v = a[z]; if (v > bv) { bv = v; best = z; } }
  elem[n] = best;
}

__global__ __launch_bounds__(256) void init_feats_kernel(const float* __restrict__ W_embed,
                                                         const int* __restrict__ elem,
                                                         ushort_t* __restrict__ F) {
  int i = blockIdx.x * 256 + threadIdx.x;   // n*128 + c
  int n = i >> 7, c = i & 127;
  F[(size_t)n * 2048 + c] = f2b(W_embed[(size_t)elem[n] * 128 + c]);
}

__global__ __launch_bounds__(256) void count_kernel(const int* __restrict__ ei, int* __restrict__ counts) {
  int e = blockIdx.x * 256 + threadIdx.x;
  if (e < kE) atomicAdd(&counts[ei[kE + e]], 1);
}

__global__ __launch_bounds__(1024) void scan_kernel(const int* __restrict__ counts, int* __restrict__ offs) {
  __shared__ int tmp[1024];
  int t = threadIdx.x;
  int loc[8]; int s = 0;
  #pragma unroll
  for (int i = 0; i < 8; ++i) { loc[i] = s; s += counts[t*8 + i]; }
  tmp[t] = s;
  __syncthreads();
  for (int d = 1; d < 1024; d <<= 1) {
    int v = (t >= d) ? tmp[t - d] : 0;
    __syncthreads();
    tmp[t] += v;
    __syncthreads();
  }
  int pre = (t == 0) ? 0 : tmp[t - 1];
  #pragma unroll
  for (int i = 0; i < 8; ++i) offs[t*8 + i] = pre + loc[i];
  if (t == 1023) offs[kN] = tmp[1023];
}

__global__ __launch_bounds__(256) void fill_kernel(const int* __restrict__ ei, const int* __restrict__ offs,
                                                   int* __restrict__ cursor, int* __restrict__ eids,
                                                   int* __restrict__ sends) {
  int e = blockIdx.x * 256 + threadIdx.x;
  if (e >= kE) return;
  int s = ei[e];
  int r = ei[kE + e];
  int pos = atomicAdd(&cursor[r], 1);
  eids[offs[r] + pos] = e;
  sends[offs[r] + pos] = s;
}

// CSR-ordered geometry: slot -> edge eids[slot]; writes sh/rb at slot.
__global__ __launch_bounds__(256) void geom_kernel(const float* __restrict__ pos,
                                                   const float* __restrict__ shifts,
                                                   const int* __restrict__ ei,
                                                   const int* __restrict__ eids,
                                                   const int* __restrict__ sends,
                                                   float* __restrict__ sh,
                                                   float* __restrict__ rb) {
  int slot = blockIdx.x * 256 + threadIdx.x;
  if (slot >= kE) return;
  int e = eids[slot];
  int s = sends[slot];
  int r = ei[kE + e];
  float vx = pos[r*3+0] - pos[s*3+0] + shifts[(size_t)e*3+0];
  float vy = pos[r*3+1] - pos[s*3+1] + shifts[(size_t)e*3+1];
  float vz = pos[r*3+2] - pos[s*3+2] + shifts[(size_t)e*3+2];
  float len = sqrtf(vx*vx + vy*vy + vz*vz) + 1e-9f;
  float inv = 1.f / len;
  float x = vx*inv, y = vy*inv, z = vz*inv;
  float x2 = x*x, y2 = y*y, z2 = z*z;
  const float s3  = 1.7320508075688772f;
  const float s5  = 2.2360679774997896f;
  const float s15 = 3.8729833462074170f;
  const float a33 = 2.0916500663351889f;
  const float a32 = 10.246950765959598f;
  const float a31 = 1.6201851746019651f;
  const float a30 = 1.3228756555322954f;
  float4* shp = (float4*)(sh + (size_t)slot * 16);
  shp[0] = make_float4(1.f, s3*x, s3*y, s3*z);
  shp[1] = make_float4(s15*x*y, s15*y*z, 0.5f*s5*(3.f*z2 - 1.f), s15*x*z);
  shp[2] = make_float4(0.5f*s15*(x2 - y2), a33*y*(3.f*x2 - y2), a32*x*y*z, a31*y*(5.f*z2 - 1.f));
  shp[3] = make_float4(a30*z*(5.f*z2 - 3.f), a31*x*(5.f*z2 - 1.f), 0.5f*a32*z*(x2 - y2), a33*x*(x2 - 3.f*y2));
  float xr = len * 0.2f;
  float cut = 0.f;
  if (xr < 1.f) {
    float x5 = xr*xr*xr*xr*xr;
    cut = 1.f - 21.f*x5 + 35.f*x5*xr - 15.f*x5*xr*xr;
  }
  float pref = 0.63245553203367587f * cut * inv;
  const float PI = 3.14159265358979323846f;
  float theta = PI * xr;
  float sn, cs;
  __sincosf(theta, &sn, &cs);
  float twoc = 2.f * cs;
  float b[8];
  float s_prev = 0.f, s_cur = sn;
  b[0] = pref * s_cur;
  #pragma unroll
  for (int k = 1; k < 8; ++k) {
    float s_next = twoc * s_cur - s_prev;
    s_prev = s_cur; s_cur = s_next;
    b[k] = pref * s_cur;
  }
  float4* rbp = (float4*)(rb + (size_t)slot * 8);
  rbp[0] = make_float4(b[0], b[1], b[2], b[3]);
  rbp[1] = make_float4(b[4], b[5], b[6], b[7]);
}

// Radial MLP, 128 slots/block. Phase 1 (K=8) on f32 VALU; phase 2 (64x64) on MFMA.
__global__ __launch_bounds__(256) void radial_kernel(const float* __restrict__ rb,
                                                     const float* __restrict__ W1,
                                                     const float* __restrict__ W2,
                                                     ushort_t* __restrict__ r2) {
  __shared__ float rbs[128][8];
  __shared__ float W1s[8*64];
  __shared__ ushort_t B2s[64][72];   // B2s[col][k] = W2[k][col], bf16
  __shared__ ushort_t r1s[128][72];  // r1 bf16 (then reused for r2 staging)
  const int tid = threadIdx.x;
  const size_t ebase = (size_t)blockIdx.x * 128;
  {
    int r = tid >> 1, q = tid & 1;
    *(float4*)&rbs[r][q*4] = *(const float4*)&rb[(ebase + r)*8 + q*4];
  }
  for (int i = tid; i < 512; i += 256) W1s[i] = W1[i];
  for (int i = tid; i < 4096; i += 256) {
    int k = i >> 6, col = i & 63;
    B2s[col][k] = f2b(W2[i]);
  }
  __syncthreads();
  {
    int col = tid & 63;
    int r0 = (tid >> 6) * 32;
    #pragma unroll 4
    for (int rr = 0; rr < 32; ++rr) {
      int row = r0 + rr;
      float v = 0.f;
      #pragma unroll
      for (int i = 0; i < 8; ++i) v = fmaf(rbs[row][i], W1s[i*64 + col], v);
      r1s[row][col] = f2b(silu_f(v));
    }
  }
  __syncthreads();
  const int lane = tid & 63, wv = tid >> 6;
  const int wr = wv * 32;
  const int fr = lane & 15, kg = (lane >> 4) * 8;
  f32x4 acc[2][4] = {};
  #pragma unroll
  for (int ks = 0; ks < 2; ++ks) {
    const int k0 = ks*32 + kg;
    bf16x8 af[2], bfr[4];
    #pragma unroll
    for (int i = 0; i < 2; ++i) af[i] = *(const bf16x8*)&r1s[wr + i*16 + fr][k0];
    #pragma unroll
    for (int j = 0; j < 4; ++j) bfr[j] = *(const bf16x8*)&B2s[j*16 + fr][k0];
    #pragma unroll
    for (int i = 0; i < 2; ++i)
      #pragma unroll
      for (int j = 0; j < 4; ++j)
        acc[i][j] = __builtin_amdgcn_mfma_f32_16x16x32_bf16(af[i], bfr[j], acc[i][j], 0, 0, 0);
  }
  __syncthreads();
  const int dcol = lane & 15, drow4 = (lane >> 4) * 4;
  #pragma unroll
  for (int i = 0; i < 2; ++i)
    #pragma unroll
    for (int j = 0; j < 4; ++j)
      #pragma unroll
      for (int r = 0; r < 4; ++r) {
        int row = wr + i*16 + drow4 + r;
        int col = j*16 + dcol;
        r1s[row][col] = f2b(silu_f(acc[i][j][r]));
      }
  __syncthreads();
  for (int idx = tid * 8; idx < 128*64; idx += 256*8) {
    int r = idx >> 6, k = idx & 63;
    *(int4*)&r2[(ebase + r)*64 + k] = *(const int4*)&r1s[r][k];
  }
}

// WT[d][c] = W[c][d], bf16.  (128x128)
__global__ __launch_bounds__(256) void transpose_w_kernel(const float* __restrict__ W, ushort_t* __restrict__ WT) {
  int i = blockIdx.x * 256 + threadIdx.x;   // d*128 + c
  int d = i >> 7, c = i & 127;
  WT[i] = f2b(W[c*128 + d]);
}

// R3T[t][j] = R_w3[j][c*4+l] with t = l*128 + c.  t in [0,512), j in [0,64)
__global__ __launch_bounds__(256) void transpose_r3_kernel(const float* __restrict__ R3, ushort_t* __restrict__ R3T) {
  int i = blockIdx.x * 256 + threadIdx.x;   // t*64 + j
  int t = i >> 6, j = i & 63;
  int c = t & 127, l = t >> 7;
  R3T[i] = f2b(R3[j*512 + c*4 + l]);
}

// MFMA GEMM (K=128): O[row, col] = sum_k A[row,k] * BT[col,k].
template<bool SCALED, bool EPI, bool L0>
__global__ __launch_bounds__(256) void mgemm_kernel(
    const ushort_t* __restrict__ A, size_t aStride,
    const ushort_t* __restrict__ BT,
    ushort_t* __restrict__ O, size_t oStride,
    const float* __restrict__ scaleBuf,
    const ushort_t* __restrict__ Hbuf,
    const float* __restrict__ wscL,
    const int* __restrict__ elem)
{
  __shared__ ushort_t As[128][136];
  __shared__ ushort_t Bs[128][136];
  const int tid = threadIdx.x;
  const size_t rowbase = (size_t)blockIdx.x * 128;

  for (int idx = tid * 8; idx < 128 * 128; idx += 256 * 8) {
    int r = idx >> 7, k = idx & 127;
    *(int4*)&Bs[r][k] = *(const int4*)&BT[(size_t)r * 128 + k];
  }
  for (int idx = tid * 8; idx < 128 * 128; idx += 256 * 8) {
    int r = idx >> 7, k = idx & 127;
    size_t grow = rowbase + r;
    const ushort_t* ap = A + grow * aStride + k;
    if (SCALED) {
      const float* sp = scaleBuf + (grow >> 4) * 128 + k;
      uint_t u[4];
      #pragma unroll
      for (int q = 0; q < 4; ++q) {
        ushort_t lo = f2b(b2f(ap[2*q])   * sp[2*q]);
        ushort_t hi = f2b(b2f(ap[2*q+1]) * sp[2*q+1]);
        u[q] = (uint_t)lo | ((uint_t)hi << 16);
      }
      *(int4*)&As[r][k] = make_int4((int)u[0], (int)u[1], (int)u[2], (int)u[3]);
    } else {
      *(int4*)&As[r][k] = *(const int4*)ap;
    }
  }
  __syncthreads();

  const int lane = tid & 63, wv = tid >> 6;
  const int wr = (wv >> 1) * 64, wc = (wv & 1) * 64;
  const int fr = lane & 15;
  const int kg = (lane >> 4) * 8;
  f32x4 acc[4][4] = {};
  #pragma unroll
  for (int ks = 0; ks < 4; ++ks) {
    const int k0 = ks * 32 + kg;
    bf16x8 af[4], bfr[4];
    #pragma unroll
    for (int i = 0; i < 4; ++i) af[i]  = *(const bf16x8*)&As[wr + i*16 + fr][k0];
    #pragma unroll
    for (int j = 0; j < 4; ++j) bfr[j] = *(const bf16x8*)&Bs[wc + j*16 + fr][k0];
    #pragma unroll
    for (int i = 0; i < 4; ++i)
      #pragma unroll
      for (int j = 0; j < 4; ++j)
        acc[i][j] = __builtin_amdgcn_mfma_f32_16x16x32_bf16(af[i], bfr[j], acc[i][j], 0, 0, 0);
  }

  const int dcol = lane & 15, drow4 = (lane >> 4) * 4;
  #pragma unroll
  for (int i = 0; i < 4; ++i) {
    #pragma unroll
    for (int j = 0; j < 4; ++j) {
      int col = wc + j*16 + dcol;
      #pragma unroll
      for (int r = 0; r < 4; ++r) {
        int row = wr + i*16 + drow4 + r;
        size_t grow = rowbase + row;
        float v = acc[i][j][r];
        if (EPI) {
          if (!L0 || ((grow & 15) == 0)) {
            int ee = elem[grow >> 4];
            v += b2f(Hbuf[grow * 128 + col]) * wscL[(size_t)ee * 128 + col];
          }
        }
        O[grow * oStride + col] = f2b(v);
      }
    }
  }
}

// Fused w-projection + gather, c-split. Grid (kN/NPB, 2); 256 thr = 4 waves.
// Block handles c-half cbb = blockIdx.y*64. Wave wid = l (0..3). B-fragments
// read straight from global R3T (L2-hot, loop-invariant -> VGPR-hoisted).
// Double-buffered per-node staging of r2/h0/sh in LDS (~21 KB total).
__global__ __launch_bounds__(256, 4) void gather_kernel(
    const int* __restrict__ offs, const int* __restrict__ sends,
    const ushort_t* __restrict__ r2csr,
    const float* __restrict__ shcsr,
    const ushort_t* __restrict__ R3T,
    const ushort_t* __restrict__ H,
    ushort_t* __restrict__ AGG)
{
  __shared__ ushort_t r2s[2][32][68];  //  8.5 KB
  __shared__ ushort_t h0s[2][32][68];  //  8.5 KB (this block's 64 c's)
  __shared__ float    shs[2][32][17];  //  4.3 KB (pad 17: kills 4-way bank conflict)
  const int tid = threadIdx.x;
  const int lane = tid & 63;
  const int l = tid >> 6;              // wave id == l, wave-uniform
  const int cbb = blockIdx.y * 64;     // block's c-half base
  const int mb = l * l, mc = 2 * l + 1;
  const int fr = lane & 15, g = lane >> 4, kg = g * 8;
  const int n0 = blockIdx.x * NPB;
  const int hslot = tid >> 3, hseg = tid & 7;   // 32 rows x 8 int4 (r2 & h0)
  const int s0i = tid, s1i = 256 + tid;         // sh: 2 floats per thread

  // B fragments: loop-invariant, straight from global (L2-hot 64 KB table)
  bf16x8 bfrag[4][2];
  #pragma unroll
  for (int j = 0; j < 4; ++j)
    #pragma unroll
    for (int ks = 0; ks < 2; ++ks)
      bfrag[j][ks] = *(const bf16x8*)&R3T[(size_t)(l*128 + cbb + j*16 + fr) * 64 + ks*32 + kg];

  // prologue: stage node n0 into buf 0 (zero-padded)
  {
    int a0 = offs[n0], a1 = offs[n0 + 1];
    int4 h0v = make_int4(0,0,0,0), r2v = make_int4(0,0,0,0);
    float sv0 = 0.f, sv1 = 0.f;
    if (a0 + hslot < a1) {
      h0v = *(const int4*)&H[(size_t)sends[a0 + hslot] * 2048 + cbb + hseg * 8];
      r2v = *(const int4*)&r2csr[(size_t)(a0 + hslot) * 64 + hseg * 8];
    }
    if (a0 + (s0i >> 4) < a1) sv0 = shcsr[(size_t)(a0 + (s0i >> 4)) * 16 + (s0i & 15)];
    if (a0 + (s1i >> 4) < a1) sv1 = shcsr[(size_t)(a0 + (s1i >> 4)) * 16 + (s1i & 15)];
    *(int4*)&h0s[0][hslot][hseg * 8] = h0v;
    *(int4*)&r2s[0][hslot][hseg * 8] = r2v;
    shs[0][s0i >> 4][s0i & 15] = sv0;
    shs[0][s1i >> 4][s1i & 15] = sv1;
  }
  __syncthreads();

  int p = 0;
  for (int nn = n0; nn < n0 + NPB; ++nn) {
    const int e0n = offs[nn], e1n = offs[nn + 1];
    // issue next-node loads early (hidden under compute)
    int4 h0n = make_int4(0,0,0,0), r2n = make_int4(0,0,0,0);
    float sn0 = 0.f, sn1 = 0.f;
    if (nn + 1 < n0 + NPB) {
      int a0 = offs[nn + 1], a1 = offs[nn + 2];
      if (a0 + hslot < a1) {
        h0n = *(const int4*)&H[(size_t)sends[a0 + hslot] * 2048 + cbb + hseg * 8];
        r2n = *(const int4*)&r2csr[(size_t)(a0 + hslot) * 64 + hseg * 8];
      }
      if (a0 + (s0i >> 4) < a1) sn0 = shcsr[(size_t)(a0 + (s0i >> 4)) * 16 + (s0i & 15)];
      if (a0 + (s1i >> 4) < a1) sn1 = shcsr[(size_t)(a0 + (s1i >> 4)) * 16 + (s1i & 15)];
    }

    float agg[7][4] = {};
    auto compute = [&](int pb) {
      f32x4 acc[2][4] = {};
      #pragma unroll
      for (int ks = 0; ks < 2; ++ks) {
        bf16x8 af[2];
        #pragma unroll
        for (int i = 0; i < 2; ++i) af[i] = *(const bf16x8*)&r2s[pb][i*16 + fr][ks*32 + kg];
        #pragma unroll
        for (int i = 0; i < 2; ++i)
          #pragma unroll
          for (int j = 0; j < 4; ++j)
            acc[i][j] = __builtin_amdgcn_mfma_f32_16x16x32_bf16(af[i], bfrag[j][ks], acc[i][j], 0, 0, 0);
      }
      #pragma unroll
      for (int i = 0; i < 2; ++i)
        #pragma unroll
        for (int r = 0; r < 4; ++r) {
          int slot = i*16 + g*4 + r;
          float shr[7];
          #pragma unroll
          for (int mi = 0; mi < 7; ++mi) shr[mi] = shs[pb][slot][mb + mi];  // mb+mi <= 15
          #pragma unroll
          for (int j = 0; j < 4; ++j) {
            float wh = acc[i][j][r] * b2f(h0s[pb][slot][j*16 + fr]);
            #pragma unroll
            for (int mi = 0; mi < 7; ++mi)
              if (mi < mc) agg[mi][j] = fmaf(wh, shr[mi], agg[mi][j]);
          }
        }
    };
    compute(p);
    // rare path: nodes with >32 edges, single-buffered extra chunks in buf p
    for (int base = e0n + 32; base < e1n; base += 32) {
      __syncthreads();
      int4 h0x = make_int4(0,0,0,0), r2x = make_int4(0,0,0,0);
      float sx0 = 0.f, sx1 = 0.f;
      if (base + hslot < e1n) {
        h0x = *(const int4*)&H[(size_t)sends[base + hslot] * 2048 + cbb + hseg * 8];
        r2x = *(const int4*)&r2csr[(size_t)(base + hslot) * 64 + hseg * 8];
      }
      if (base + (s0i >> 4) < e1n) sx0 = shcsr[(size_t)(base + (s0i >> 4)) * 16 + (s0i & 15)];
      if (base + (s1i >> 4) < e1n) sx1 = shcsr[(size_t)(base + (s1i >> 4)) * 16 + (s1i & 15)];
      *(int4*)&h0s[p][hslot][hseg * 8] = h0x;
      *(int4*)&r2s[p][hslot][hseg * 8] = r2x;
      shs[p][s0i >> 4][s0i & 15] = sx0;
      shs[p][s1i >> 4][s1i & 15] = sx1;
      __syncthreads();
      compute(p);
    }
    // reduce over the 4 edge-groups and write AGG for node nn
    #pragma unroll
    for (int mi = 0; mi < 7; ++mi) {
      if (mi < mc) {
        #pragma unroll
        for (int j = 0; j < 4; ++j) {
          float v = agg[mi][j];
          v += __shfl_xor(v, 16, 64);
          v += __shfl_xor(v, 32, 64);
          if (lane < 16)
            AGG[(size_t)nn * 2048 + (mb + mi) * 128 + cbb + j * 16 + lane] = f2b(v * 0.0625f);
        }
      }
    }
    // land next-node staged regs into buf p^1
    *(int4*)&h0s[p ^ 1][hslot][hseg * 8] = h0n;
    *(int4*)&r2s[p ^ 1][hslot][hseg * 8] = r2n;
    shs[p ^ 1][s0i >> 4][s0i & 15] = sn0;
    shs[p ^ 1][s1i >> 4][s1i & 15] = sn1;
    __syncthreads();
    p ^= 1;
  }
}

__global__ __launch_bounds__(256) void scale_kernel(const ushort_t* __restrict__ M,
                                                    const int* __restrict__ elem,
                                                    const float* __restrict__ wprodL,
                                                    float* __restrict__ scale) {
  int i = blockIdx.x * 256 + threadIdx.x;  // n*128 + c
  int n = i >> 7, c = i & 127;
  float s = b2f(M[(size_t)n * 2048 + c]);
  const float* co = wprodL + ((size_t)elem[n] * 128 + c) * 3;
  scale[i] = co[0] + s * (co[1] + s * co[2]);
}

__global__ __launch_bounds__(64) void readout_kernel(const ushort_t* __restrict__ F,
                                                     const float* __restrict__ ro0,
                                                     const float* __restrict__ ro1,
                                                     const float* __restrict__ ro2,
                                                     float* __restrict__ out, int layer) {
  int n = blockIdx.x; int t = threadIdx.x;
  const ushort_t* fr = F + (size_t)n * 2048;   // feats[n][0][:]
  float f0 = b2f(fr[t]), f1 = b2f(fr[t + 64]);
  if (layer == 0) {
    float v = f0 * ro0[t] + f1 * ro0[t + 64];
    #pragma unroll
    for (int m = 32; m > 0; m >>= 1) v += __shfl_xor(v, m, 64);
    if (t == 0) out[n] = v;
  } else {
    float acc = 0.f;
    for (int h = 0; h < 16; ++h) {
      float p = f0 * ro1[t*16 + h] + f1 * ro1[(t + 64)*16 + h];
      #pragma unroll
      for (int m = 32; m > 0; m >>= 1) p += __shfl_xor(p, m, 64);
      acc = fmaf(silu_f(p), ro2[h], acc);
    }
    if (t == 0) out[n] += acc;
  }
}

extern "C" void kernel_launch(void* const* d_in, const int* in_sizes, int n_in,
                              void* d_out, int out_size, void* d_ws, size_t ws_size,
                              hipStream_t stream) {
  (void)in_sizes; (void)n_in; (void)out_size;
  const float* positions = (const float*)d_in[0];
  const float* node_attrs= (const float*)d_in[1];
  const float* shifts    = (const float*)d_in[2];
  const float* W_embed   = (const float*)d_in[3];
  const float* W_up      = (const float*)d_in[4];
  const float* R_w1      = (const float*)d_in[5];
  const float* R_w2      = (const float*)d_in[6];
  const float* R_w3      = (const float*)d_in[7];
  const float* W_out     = (const float*)d_in[8];
  const float* w_sc      = (const float*)d_in[9];
  const float* w_prod    = (const float*)d_in[10];
  const float* W_plin    = (const float*)d_in[11];
  const float* w_ro0     = (const float*)d_in[12];
  const float* ro_w1     = (const float*)d_in[13];
  const float* ro_w2     = (const float*)d_in[14];
  const int*   ei        = (const int*)d_in[15];
  float* out = (float*)d_out;

  char* ws_ptr = (char*)d_ws;
  size_t off = 0;
  auto alloc = [&](size_t nbytes) -> void* {
    void* p = ws_ptr + off;
    off += (nbytes + 255) & ~(size_t)255;
    return p;
  };
  const size_t PB = (size_t)kN * 16 * 128 * sizeof(ushort_t);  // 33.5 MB
  ushort_t* P0    = (ushort_t*)alloc(PB);
  ushort_t* P1    = (ushort_t*)alloc(PB);
  ushort_t* P2    = (ushort_t*)alloc(PB);
  float* shcsr    = (float*)alloc((size_t)kE * 16 * 4);          // 8.4 MB
  float* rbcsr    = (float*)alloc((size_t)kE * 8 * 4);           // 4.2 MB
  ushort_t* r2csr = (ushort_t*)alloc((size_t)kE * 64 * 2);       // 16.8 MB
  float* scaleb   = (float*)alloc((size_t)kN * 128 * 4);         // 4.2 MB
  ushort_t* R3T0  = (ushort_t*)alloc(512 * 64 * 2);
  ushort_t* R3T1  = (ushort_t*)alloc(512 * 64 * 2);
  ushort_t* WTu0  = (ushort_t*)alloc(128 * 128 * 2);
  ushort_t* WTu1  = (ushort_t*)alloc(128 * 128 * 2);
  ushort_t* WTo0  = (ushort_t*)alloc(128 * 128 * 2);
  ushort_t* WTo1  = (ushort_t*)alloc(128 * 128 * 2);
  ushort_t* WTp0  = (ushort_t*)alloc(128 * 128 * 2);
  ushort_t* WTp1  = (ushort_t*)alloc(128 * 128 * 2);
  int* elemb  = (int*)alloc(kN * 4);
  int* counts = (int*)alloc(kN * 4);
  int* cursor = (int*)alloc(kN * 4);
  int* offsb  = (int*)alloc((kN + 1) * 4);
  int* eidsb  = (int*)alloc((size_t)kE * 4);
  int* sendsb = (int*)alloc((size_t)kE * 4);
  if (off > ws_size) return;  // ~136 MB total

  // ---- prep ----
  zero_ints_kernel<<<kN/256, 256, 0, stream>>>(counts, cursor);
  elem_kernel<<<kN/256, 256, 0, stream>>>(node_attrs, elemb);
  init_feats_kernel<<<(kN*128)/256, 256, 0, stream>>>(W_embed, elemb, P0);
  count_kernel<<<kE/256, 256, 0, stream>>>(ei, counts);
  scan_kernel<<<1, 1024, 0, stream>>>(counts, offsb);
  fill_kernel<<<kE/256, 256, 0, stream>>>(ei, offsb, cursor, eidsb, sendsb);
  geom_kernel<<<kE/256, 256, 0, stream>>>(positions, shifts, ei, eidsb, sendsb, shcsr, rbcsr);
  transpose_w_kernel<<<64, 256, 0, stream>>>(W_up, WTu0);
  transpose_w_kernel<<<64, 256, 0, stream>>>(W_up + 16384, WTu1);
  transpose_w_kernel<<<64, 256, 0, stream>>>(W_out, WTo0);
  transpose_w_kernel<<<64, 256, 0, stream>>>(W_out + 16384, WTo1);
  transpose_w_kernel<<<64, 256, 0, stream>>>(W_plin, WTp0);
  transpose_w_kernel<<<64, 256, 0, stream>>>(W_plin + 16384, WTp1);
  transpose_r3_kernel<<<128, 256, 0, stream>>>(R_w3, R3T0);
  transpose_r3_kernel<<<128, 256, 0, stream>>>(R_w3 + 32768, R3T1);

  // ---- layer 0 (feats nonzero only at m=0) ----
  radial_kernel<<<kE/128, 256, 0, stream>>>(rbcsr, R_w1, R_w2, r2csr);
  mgemm_kernel<false,false,false><<<kN/128, 256, 0, stream>>>(
      P0, 2048, WTu0, P1, 2048, nullptr, nullptr, nullptr, nullptr);
  gather_kernel<<<dim3(kN/NPB, 2), 256, 0, stream>>>(offsb, sendsb, r2csr, shcsr, R3T0, P1, P2);
  mgemm_kernel<false,false,false><<<(kN*16)/128, 256, 0, stream>>>(
      P2, 128, WTo0, P0, 128, nullptr, nullptr, nullptr, nullptr);
  scale_kernel<<<(kN*128)/256, 256, 0, stream>>>(P0, elemb, w_prod, scaleb);
  mgemm_kernel<true,true,true><<<(kN*16)/128, 256, 0, stream>>>(
      P0, 128, WTp0, P2, 128, scaleb, P1, w_sc, elemb);
  readout_kernel<<<kN, 64, 0, stream>>>(P2, w_ro0, ro_w1, ro_w2, out, 0);

  // ---- layer 1 ----
  radial_kernel<<<kE/128, 256, 0, stream>>>(rbcsr, R_w1 + 512, R_w2 + 4096, r2csr);
  mgemm_kernel<false,false,false><<<(kN*16)/128, 256, 0, stream>>>(
      P2, 128, WTu1, P1, 128, nullptr, nullptr, nullptr, nullptr);
  gather_kernel<<<dim3(kN/NPB, 2), 256, 0, stream>>>(offsb, sendsb, r2csr, shcsr, R3T1, P1, P0);
  mgemm_kernel<false,false,false><<<(kN*16)/128, 256, 0, stream>>>(
      P0, 128, WTo1, P2, 128, nullptr, nullptr, nullptr, nullptr);
  scale_kernel<<<(kN*128)/256, 256, 0, stream>>>(P2, elemb, w_prod + 3840, scaleb);
  mgemm_kernel<true,true,false><<<(kN*16)/128, 256, 0, stream>>>(
      P2, 128, WTp1, P0, 128, scaleb, P1, w_sc + 1280, elemb);
  readout_kernel<<<kN, 64, 0, stream>>>(P0, w_ro0, ro_w1, ro_w2, out, 1);
}

// Round 14
// 492.413 us; speedup vs baseline: 1.0417x; 1.0417x over previous
//
#include <hip/hip_runtime.h>
#include <math.h>

constexpr int kN = 8192;
constexpr int kE = 131072;
constexpr int NPB = 16;   // nodes per gather block

typedef short bf16x8 __attribute__((ext_vector_type(8)));
typedef float f32x4 __attribute__((ext_vector_type(4)));
typedef unsigned short ushort_t;
typedef unsigned int uint_t;

__device__ __forceinline__ float silu_f(float x) { return x / (1.f + __expf(-x)); }

__device__ __forceinline__ ushort_t f2b(float f) {
  uint_t x = __float_as_uint(f);
  uint_t r = (x + 0x7fffu + ((x >> 16) & 1u)) >> 16;
  return (ushort_t)r;
}
__device__ __forceinline__ float b2f(ushort_t u) {
  return __uint_as_float(((uint_t)u) << 16);
}

__global__ __launch_bounds__(256) void zero_ints_kernel(int* __restrict__ a, int* __restrict__ b) {
  int i = blockIdx.x * 256 + threadIdx.x;
  if (i < kN) { a[i] = 0; b[i] = 0; }
}

__global__ __launch_bounds__(256) void elem_kernel(const float* __restrict__ attrs, int* __restrict__ elem) {
  int n = blockIdx.x * 256 + threadIdx.x;
  if (n >= kN) return;
  const float* a = attrs + (size_t)n * 10;
  int best = 0; float bv = a[0];
  #pragma unroll
  for (int z = 1; z < 10; ++z) { float v = a[z]; if (v > bv) { bv = v; best = z; } }
  elem[n] = best;
}

__global__ __launch_bounds__(256) void init_feats_kernel(const float* __restrict__ W_embed,
                                                         const int* __restrict__ elem,
                                                         ushort_t* __restrict__ F) {
  int i = blockIdx.x * 256 + threadIdx.x;   // n*128 + c
  int n = i >> 7, c = i & 127;
  F[(size_t)n * 2048 + c] = f2b(W_embed[(size_t)elem[n] * 128 + c]);
}

__global__ __launch_bounds__(256) void count_kernel(const int* __restrict__ ei, int* __restrict__ counts) {
  int e = blockIdx.x * 256 + threadIdx.x;
  if (e < kE) atomicAdd(&counts[ei[kE + e]], 1);
}

__global__ __launch_bounds__(1024) void scan_kernel(const int* __restrict__ counts, int* __restrict__ offs) {
  __shared__ int tmp[1024];
  int t = threadIdx.x;
  int loc[8]; int s = 0;
  #pragma unroll
  for (int i = 0; i < 8; ++i) { loc[i] = s; s += counts[t*8 + i]; }
  tmp[t] = s;
  __syncthreads();
  for (int d = 1; d < 1024; d <<= 1) {
    int v = (t >= d) ? tmp[t - d] : 0;
    __syncthreads();
    tmp[t] += v;
    __syncthreads();
  }
  int pre = (t == 0) ? 0 : tmp[t - 1];
  #pragma unroll
  for (int i = 0; i < 8; ++i) offs[t*8 + i] = pre + loc[i];
  if (t == 1023) offs[kN] = tmp[1023];
}

__global__ __launch_bounds__(256) void fill_kernel(const int* __restrict__ ei, const int* __restrict__ offs,
                                                   int* __restrict__ cursor, int* __restrict__ eids,
                                                   int* __restrict__ sends) {
  int e = blockIdx.x * 256 + threadIdx.x;
  if (e >= kE) return;
  int s = ei[e];
  int r = ei[kE + e];
  int pos = atomicAdd(&cursor[r], 1);
  eids[offs[r] + pos] = e;
  sends[offs[r] + pos] = s;
}

// CSR-ordered geometry: slot -> edge eids[slot]; writes sh/rb at slot.
__global__ __launch_bounds__(256) void geom_kernel(const float* __restrict__ pos,
                                                   const float* __restrict__ shifts,
                                                   const int* __restrict__ ei,
                                                   const int* __restrict__ eids,
                                                   const int* __restrict__ sends,
                                                   float* __restrict__ sh,
                                                   float* __restrict__ rb) {
  int slot = blockIdx.x * 256 + threadIdx.x;
  if (slot >= kE) return;
  int e = eids[slot];
  int s = sends[slot];
  int r = ei[kE + e];
  float vx = pos[r*3+0] - pos[s*3+0] + shifts[(size_t)e*3+0];
  float vy = pos[r*3+1] - pos[s*3+1] + shifts[(size_t)e*3+1];
  float vz = pos[r*3+2] - pos[s*3+2] + shifts[(size_t)e*3+2];
  float len = sqrtf(vx*vx + vy*vy + vz*vz) + 1e-9f;
  float inv = 1.f / len;
  float x = vx*inv, y = vy*inv, z = vz*inv;
  float x2 = x*x, y2 = y*y, z2 = z*z;
  const float s3  = 1.7320508075688772f;
  const float s5  = 2.2360679774997896f;
  const float s15 = 3.8729833462074170f;
  const float a33 = 2.0916500663351889f;
  const float a32 = 10.246950765959598f;
  const float a31 = 1.6201851746019651f;
  const float a30 = 1.3228756555322954f;
  float4* shp = (float4*)(sh + (size_t)slot * 16);
  shp[0] = make_float4(1.f, s3*x, s3*y, s3*z);
  shp[1] = make_float4(s15*x*y, s15*y*z, 0.5f*s5*(3.f*z2 - 1.f), s15*x*z);
  shp[2] = make_float4(0.5f*s15*(x2 - y2), a33*y*(3.f*x2 - y2), a32*x*y*z, a31*y*(5.f*z2 - 1.f));
  shp[3] = make_float4(a30*z*(5.f*z2 - 3.f), a31*x*(5.f*z2 - 1.f), 0.5f*a32*z*(x2 - y2), a33*x*(x2 - 3.f*y2));
  float xr = len * 0.2f;
  float cut = 0.f;
  if (xr < 1.f) {
    float x5 = xr*xr*xr*xr*xr;
    cut = 1.f - 21.f*x5 + 35.f*x5*xr - 15.f*x5*xr*xr;
  }
  float pref = 0.63245553203367587f * cut * inv;
  const float PI = 3.14159265358979323846f;
  float theta = PI * xr;
  float sn, cs;
  __sincosf(theta, &sn, &cs);
  float twoc = 2.f * cs;
  float b[8];
  float s_prev = 0.f, s_cur = sn;
  b[0] = pref * s_cur;
  #pragma unroll
  for (int k = 1; k < 8; ++k) {
    float s_next = twoc * s_cur - s_prev;
    s_prev = s_cur; s_cur = s_next;
    b[k] = pref * s_cur;
  }
  float4* rbp = (float4*)(rb + (size_t)slot * 8);
  rbp[0] = make_float4(b[0], b[1], b[2], b[3]);
  rbp[1] = make_float4(b[4], b[5], b[6], b[7]);
}

// Radial MLP, 128 slots/block. Phase 1 (K=8) on f32 VALU; phase 2 (64x64) on MFMA.
__global__ __launch_bounds__(256) void radial_kernel(const float* __restrict__ rb,
                                                     const float* __restrict__ W1,
                                                     const float* __restrict__ W2,
                                                     ushort_t* __restrict__ r2) {
  __shared__ float rbs[128][8];
  __shared__ float W1s[8*64];
  __shared__ ushort_t B2s[64][72];   // B2s[col][k] = W2[k][col], bf16
  __shared__ ushort_t r1s[128][72];  // r1 bf16 (then reused for r2 staging)
  const int tid = threadIdx.x;
  const size_t ebase = (size_t)blockIdx.x * 128;
  {
    int r = tid >> 1, q = tid & 1;
    *(float4*)&rbs[r][q*4] = *(const float4*)&rb[(ebase + r)*8 + q*4];
  }
  for (int i = tid; i < 512; i += 256) W1s[i] = W1[i];
  for (int i = tid; i < 4096; i += 256) {
    int k = i >> 6, col = i & 63;
    B2s[col][k] = f2b(W2[i]);
  }
  __syncthreads();
  {
    int col = tid & 63;
    int r0 = (tid >> 6) * 32;
    #pragma unroll 4
    for (int rr = 0; rr < 32; ++rr) {
      int row = r0 + rr;
      float v = 0.f;
      #pragma unroll
      for (int i = 0; i < 8; ++i) v = fmaf(rbs[row][i], W1s[i*64 + col], v);
      r1s[row][col] = f2b(silu_f(v));
    }
  }
  __syncthreads();
  const int lane = tid & 63, wv = tid >> 6;
  const int wr = wv * 32;
  const int fr = lane & 15, kg = (lane >> 4) * 8;
  f32x4 acc[2][4] = {};
  #pragma unroll
  for (int ks = 0; ks < 2; ++ks) {
    const int k0 = ks*32 + kg;
    bf16x8 af[2], bfr[4];
    #pragma unroll
    for (int i = 0; i < 2; ++i) af[i] = *(const bf16x8*)&r1s[wr + i*16 + fr][k0];
    #pragma unroll
    for (int j = 0; j < 4; ++j) bfr[j] = *(const bf16x8*)&B2s[j*16 + fr][k0];
    #pragma unroll
    for (int i = 0; i < 2; ++i)
      #pragma unroll
      for (int j = 0; j < 4; ++j)
        acc[i][j] = __builtin_amdgcn_mfma_f32_16x16x32_bf16(af[i], bfr[j], acc[i][j], 0, 0, 0);
  }
  __syncthreads();
  const int dcol = lane & 15, drow4 = (lane >> 4) * 4;
  #pragma unroll
  for (int i = 0; i < 2; ++i)
    #pragma unroll
    for (int j = 0; j < 4; ++j)
      #pragma unroll
      for (int r = 0; r < 4; ++r) {
        int row = wr + i*16 + drow4 + r;
        int col = j*16 + dcol;
        r1s[row][col] = f2b(silu_f(acc[i][j][r]));
      }
  __syncthreads();
  for (int idx = tid * 8; idx < 128*64; idx += 256*8) {
    int r = idx >> 6, k = idx & 63;
    *(int4*)&r2[(ebase + r)*64 + k] = *(const int4*)&r1s[r][k];
  }
}

// WT[d][c] = W[c][d], bf16.  (128x128)
__global__ __launch_bounds__(256) void transpose_w_kernel(const float* __restrict__ W, ushort_t* __restrict__ WT) {
  int i = blockIdx.x * 256 + threadIdx.x;   // d*128 + c
  int d = i >> 7, c = i & 127;
  WT[i] = f2b(W[c*128 + d]);
}

// R3T[t][j] = R_w3[j][c*4+l] with t = l*128 + c.  t in [0,512), j in [0,64)
__global__ __launch_bounds__(256) void transpose_r3_kernel(const float* __restrict__ R3, ushort_t* __restrict__ R3T) {
  int i = blockIdx.x * 256 + threadIdx.x;   // t*64 + j
  int t = i >> 6, j = i & 63;
  int c = t & 127, l = t >> 7;
  R3T[i] = f2b(R3[j*512 + c*4 + l]);
}

// MFMA GEMM (K=128): O[row, col] = sum_k A[row,k] * BT[col,k].
template<bool SCALED, bool EPI, bool L0>
__global__ __launch_bounds__(256) void mgemm_kernel(
    const ushort_t* __restrict__ A, size_t aStride,
    const ushort_t* __restrict__ BT,
    ushort_t* __restrict__ O, size_t oStride,
    const float* __restrict__ scaleBuf,
    const ushort_t* __restrict__ Hbuf,
    const float* __restrict__ wscL,
    const int* __restrict__ elem)
{
  __shared__ ushort_t As[128][136];
  __shared__ ushort_t Bs[128][136];
  const int tid = threadIdx.x;
  const size_t rowbase = (size_t)blockIdx.x * 128;

  for (int idx = tid * 8; idx < 128 * 128; idx += 256 * 8) {
    int r = idx >> 7, k = idx & 127;
    *(int4*)&Bs[r][k] = *(const int4*)&BT[(size_t)r * 128 + k];
  }
  for (int idx = tid * 8; idx < 128 * 128; idx += 256 * 8) {
    int r = idx >> 7, k = idx & 127;
    size_t grow = rowbase + r;
    const ushort_t* ap = A + grow * aStride + k;
    if (SCALED) {
      const float* sp = scaleBuf + (grow >> 4) * 128 + k;
      uint_t u[4];
      #pragma unroll
      for (int q = 0; q < 4; ++q) {
        ushort_t lo = f2b(b2f(ap[2*q])   * sp[2*q]);
        ushort_t hi = f2b(b2f(ap[2*q+1]) * sp[2*q+1]);
        u[q] = (uint_t)lo | ((uint_t)hi << 16);
      }
      *(int4*)&As[r][k] = make_int4((int)u[0], (int)u[1], (int)u[2], (int)u[3]);
    } else {
      *(int4*)&As[r][k] = *(const int4*)ap;
    }
  }
  __syncthreads();

  const int lane = tid & 63, wv = tid >> 6;
  const int wr = (wv >> 1) * 64, wc = (wv & 1) * 64;
  const int fr = lane & 15;
  const int kg = (lane >> 4) * 8;
  f32x4 acc[4][4] = {};
  #pragma unroll
  for (int ks = 0; ks < 4; ++ks) {
    const int k0 = ks * 32 + kg;
    bf16x8 af[4], bfr[4];
    #pragma unroll
    for (int i = 0; i < 4; ++i) af[i]  = *(const bf16x8*)&As[wr + i*16 + fr][k0];
    #pragma unroll
    for (int j = 0; j < 4; ++j) bfr[j] = *(const bf16x8*)&Bs[wc + j*16 + fr][k0];
    #pragma unroll
    for (int i = 0; i < 4; ++i)
      #pragma unroll
      for (int j = 0; j < 4; ++j)
        acc[i][j] = __builtin_amdgcn_mfma_f32_16x16x32_bf16(af[i], bfr[j], acc[i][j], 0, 0, 0);
  }

  const int dcol = lane & 15, drow4 = (lane >> 4) * 4;
  #pragma unroll
  for (int i = 0; i < 4; ++i) {
    #pragma unroll
    for (int j = 0; j < 4; ++j) {
      int col = wc + j*16 + dcol;
      #pragma unroll
      for (int r = 0; r < 4; ++r) {
        int row = wr + i*16 + drow4 + r;
        size_t grow = rowbase + row;
        float v = acc[i][j][r];
        if (EPI) {
          if (!L0 || ((grow & 15) == 0)) {
            int ee = elem[grow >> 4];
            v += b2f(Hbuf[grow * 128 + col]) * wscL[(size_t)ee * 128 + col];
          }
        }
        O[grow * oStride + col] = f2b(v);
      }
    }
  }
}

// Fused w-projection + gather, c-split. Grid (kN/NPB, 2); 256 thr = 4 waves.
// Block handles c-half cbb = blockIdx.y*64. Wave wid = l (0..3). B-fragments
// read straight from global R3T (L2-hot, loop-invariant -> VGPR-hoisted).
// Double-buffered per-node staging of r2/h0/sh in LDS (~21 KB total).
// launch_bounds (256,2): VGPR cap 256 -> no spills; LDS 21.5 KB + ~108 VGPR
// naturally gives 4 blocks/CU.
__global__ __launch_bounds__(256, 2) void gather_kernel(
    const int* __restrict__ offs, const int* __restrict__ sends,
    const ushort_t* __restrict__ r2csr,
    const float* __restrict__ shcsr,
    const ushort_t* __restrict__ R3T,
    const ushort_t* __restrict__ H,
    ushort_t* __restrict__ AGG)
{
  __shared__ ushort_t r2s[2][32][68];  //  8.5 KB
  __shared__ ushort_t h0s[2][32][68];  //  8.5 KB (this block's 64 c's)
  __shared__ float    shs[2][32][17];  //  4.3 KB (pad 17: kills 4-way bank conflict)
  const int tid = threadIdx.x;
  const int lane = tid & 63;
  const int l = tid >> 6;              // wave id == l, wave-uniform
  const int cbb = blockIdx.y * 64;     // block's c-half base
  const int mb = l * l, mc = 2 * l + 1;
  const int fr = lane & 15, g = lane >> 4, kg = g * 8;
  const int n0 = blockIdx.x * NPB;
  const int hslot = tid >> 3, hseg = tid & 7;   // 32 rows x 8 int4 (r2 & h0)
  const int s0i = tid, s1i = 256 + tid;         // sh: 2 floats per thread

  // B fragments: loop-invariant, straight from global (L2-hot 64 KB table)
  bf16x8 bfrag[4][2];
  #pragma unroll
  for (int j = 0; j < 4; ++j)
    #pragma unroll
    for (int ks = 0; ks < 2; ++ks)
      bfrag[j][ks] = *(const bf16x8*)&R3T[(size_t)(l*128 + cbb + j*16 + fr) * 64 + ks*32 + kg];

  // prologue: stage node n0 into buf 0 (zero-padded)
  {
    int a0 = offs[n0], a1 = offs[n0 + 1];
    int4 h0v = make_int4(0,0,0,0), r2v = make_int4(0,0,0,0);
    float sv0 = 0.f, sv1 = 0.f;
    if (a0 + hslot < a1) {
      h0v = *(const int4*)&H[(size_t)sends[a0 + hslot] * 2048 + cbb + hseg * 8];
      r2v = *(const int4*)&r2csr[(size_t)(a0 + hslot) * 64 + hseg * 8];
    }
    if (a0 + (s0i >> 4) < a1) sv0 = shcsr[(size_t)(a0 + (s0i >> 4)) * 16 + (s0i & 15)];
    if (a0 + (s1i >> 4) < a1) sv1 = shcsr[(size_t)(a0 + (s1i >> 4)) * 16 + (s1i & 15)];
    *(int4*)&h0s[0][hslot][hseg * 8] = h0v;
    *(int4*)&r2s[0][hslot][hseg * 8] = r2v;
    shs[0][s0i >> 4][s0i & 15] = sv0;
    shs[0][s1i >> 4][s1i & 15] = sv1;
  }
  __syncthreads();

  int p = 0;
  for (int nn = n0; nn < n0 + NPB; ++nn) {
    const int e0n = offs[nn], e1n = offs[nn + 1];
    // issue next-node loads early (hidden under compute)
    int4 h0n = make_int4(0,0,0,0), r2n = make_int4(0,0,0,0);
    float sn0 = 0.f, sn1 = 0.f;
    if (nn + 1 < n0 + NPB) {
      int a0 = offs[nn + 1], a1 = offs[nn + 2];
      if (a0 + hslot < a1) {
        h0n = *(const int4*)&H[(size_t)sends[a0 + hslot] * 2048 + cbb + hseg * 8];
        r2n = *(const int4*)&r2csr[(size_t)(a0 + hslot) * 64 + hseg * 8];
      }
      if (a0 + (s0i >> 4) < a1) sn0 = shcsr[(size_t)(a0 + (s0i >> 4)) * 16 + (s0i & 15)];
      if (a0 + (s1i >> 4) < a1) sn1 = shcsr[(size_t)(a0 + (s1i >> 4)) * 16 + (s1i & 15)];
    }

    float agg[7][4] = {};
    auto compute = [&](int pb) {
      f32x4 acc[2][4] = {};
      #pragma unroll
      for (int ks = 0; ks < 2; ++ks) {
        bf16x8 af[2];
        #pragma unroll
        for (int i = 0; i < 2; ++i) af[i] = *(const bf16x8*)&r2s[pb][i*16 + fr][ks*32 + kg];
        #pragma unroll
        for (int i = 0; i < 2; ++i)
          #pragma unroll
          for (int j = 0; j < 4; ++j)
            acc[i][j] = __builtin_amdgcn_mfma_f32_16x16x32_bf16(af[i], bfrag[j][ks], acc[i][j], 0, 0, 0);
      }
      #pragma unroll
      for (int i = 0; i < 2; ++i)
        #pragma unroll
        for (int r = 0; r < 4; ++r) {
          int slot = i*16 + g*4 + r;
          float shr[7];
          #pragma unroll
          for (int mi = 0; mi < 7; ++mi) shr[mi] = shs[pb][slot][mb + mi];  // mb+mi <= 15
          #pragma unroll
          for (int j = 0; j < 4; ++j) {
            float wh = acc[i][j][r] * b2f(h0s[pb][slot][j*16 + fr]);
            #pragma unroll
            for (int mi = 0; mi < 7; ++mi)
              if (mi < mc) agg[mi][j] = fmaf(wh, shr[mi], agg[mi][j]);
          }
        }
    };
    compute(p);
    // rare path: nodes with >32 edges, single-buffered extra chunks in buf p
    for (int base = e0n + 32; base < e1n; base += 32) {
      __syncthreads();
      int4 h0x = make_int4(0,0,0,0), r2x = make_int4(0,0,0,0);
      float sx0 = 0.f, sx1 = 0.f;
      if (base + hslot < e1n) {
        h0x = *(const int4*)&H[(size_t)sends[base + hslot] * 2048 + cbb + hseg * 8];
        r2x = *(const int4*)&r2csr[(size_t)(base + hslot) * 64 + hseg * 8];
      }
      if (base + (s0i >> 4) < e1n) sx0 = shcsr[(size_t)(base + (s0i >> 4)) * 16 + (s0i & 15)];
      if (base + (s1i >> 4) < e1n) sx1 = shcsr[(size_t)(base + (s1i >> 4)) * 16 + (s1i & 15)];
      *(int4*)&h0s[p][hslot][hseg * 8] = h0x;
      *(int4*)&r2s[p][hslot][hseg * 8] = r2x;
      shs[p][s0i >> 4][s0i & 15] = sx0;
      shs[p][s1i >> 4][s1i & 15] = sx1;
      __syncthreads();
      compute(p);
    }
    // reduce over the 4 edge-groups and write AGG for node nn
    #pragma unroll
    for (int mi = 0; mi < 7; ++mi) {
      if (mi < mc) {
        #pragma unroll
        for (int j = 0; j < 4; ++j) {
          float v = agg[mi][j];
          v += __shfl_xor(v, 16, 64);
          v += __shfl_xor(v, 32, 64);
          if (lane < 16)
            AGG[(size_t)nn * 2048 + (mb + mi) * 128 + cbb + j * 16 + lane] = f2b(v * 0.0625f);
        }
      }
    }
    // land next-node staged regs into buf p^1
    *(int4*)&h0s[p ^ 1][hslot][hseg * 8] = h0n;
    *(int4*)&r2s[p ^ 1][hslot][hseg * 8] = r2n;
    shs[p ^ 1][s0i >> 4][s0i & 15] = sn0;
    shs[p ^ 1][s1i >> 4][s1i & 15] = sn1;
    __syncthreads();
    p ^= 1;
  }
}

__global__ __launch_bounds__(256) void scale_kernel(const ushort_t* __restrict__ M,
                                                    const int* __restrict__ elem,
                                                    const float* __restrict__ wprodL,
                                                    float* __restrict__ scale) {
  int i = blockIdx.x * 256 + threadIdx.x;  // n*128 + c
  int n = i >> 7, c = i & 127;
  float s = b2f(M[(size_t)n * 2048 + c]);
  const float* co = wprodL + ((size_t)elem[n] * 128 + c) * 3;
  scale[i] = co[0] + s * (co[1] + s * co[2]);
}

__global__ __launch_bounds__(64) void readout_kernel(const ushort_t* __restrict__ F,
                                                     const float* __restrict__ ro0,
                                                     const float* __restrict__ ro1,
                                                     const float* __restrict__ ro2,
                                                     float* __restrict__ out, int layer) {
  int n = blockIdx.x; int t = threadIdx.x;
  const ushort_t* fr = F + (size_t)n * 2048;   // feats[n][0][:]
  float f0 = b2f(fr[t]), f1 = b2f(fr[t + 64]);
  if (layer == 0) {
    float v = f0 * ro0[t] + f1 * ro0[t + 64];
    #pragma unroll
    for (int m = 32; m > 0; m >>= 1) v += __shfl_xor(v, m, 64);
    if (t == 0) out[n] = v;
  } else {
    float acc = 0.f;
    for (int h = 0; h < 16; ++h) {
      float p = f0 * ro1[t*16 + h] + f1 * ro1[(t + 64)*16 + h];
      #pragma unroll
      for (int m = 32; m > 0; m >>= 1) p += __shfl_xor(p, m, 64);
      acc = fmaf(silu_f(p), ro2[h], acc);
    }
    if (t == 0) out[n] += acc;
  }
}

extern "C" void kernel_launch(void* const* d_in, const int* in_sizes, int n_in,
                              void* d_out, int out_size, void* d_ws, size_t ws_size,
                              hipStream_t stream) {
  (void)in_sizes; (void)n_in; (void)out_size;
  const float* positions = (const float*)d_in[0];
  const float* node_attrs= (const float*)d_in[1];
  const float* shifts    = (const float*)d_in[2];
  const float* W_embed   = (const float*)d_in[3];
  const float* W_up      = (const float*)d_in[4];
  const float* R_w1      = (const float*)d_in[5];
  const float* R_w2      = (const float*)d_in[6];
  const float* R_w3      = (const float*)d_in[7];
  const float* W_out     = (const float*)d_in[8];
  const float* w_sc      = (const float*)d_in[9];
  const float* w_prod    = (const float*)d_in[10];
  const float* W_plin    = (const float*)d_in[11];
  const float* w_ro0     = (const float*)d_in[12];
  const float* ro_w1     = (const float*)d_in[13];
  const float* ro_w2     = (const float*)d_in[14];
  const int*   ei        = (const int*)d_in[15];
  float* out = (float*)d_out;

  char* ws_ptr = (char*)d_ws;
  size_t off = 0;
  auto alloc = [&](size_t nbytes) -> void* {
    void* p = ws_ptr + off;
    off += (nbytes + 255) & ~(size_t)255;
    return p;
  };
  const size_t PB = (size_t)kN * 16 * 128 * sizeof(ushort_t);  // 33.5 MB
  ushort_t* P0    = (ushort_t*)alloc(PB);
  ushort_t* P1    = (ushort_t*)alloc(PB);
  ushort_t* P2    = (ushort_t*)alloc(PB);
  float* shcsr    = (float*)alloc((size_t)kE * 16 * 4);          // 8.4 MB
  float* rbcsr    = (float*)alloc((size_t)kE * 8 * 4);           // 4.2 MB
  ushort_t* r2csr = (ushort_t*)alloc((size_t)kE * 64 * 2);       // 16.8 MB
  float* scaleb   = (float*)alloc((size_t)kN * 128 * 4);         // 4.2 MB
  ushort_t* R3T0  = (ushort_t*)alloc(512 * 64 * 2);
  ushort_t* R3T1  = (ushort_t*)alloc(512 * 64 * 2);
  ushort_t* WTu0  = (ushort_t*)alloc(128 * 128 * 2);
  ushort_t* WTu1  = (ushort_t*)alloc(128 * 128 * 2);
  ushort_t* WTo0  = (ushort_t*)alloc(128 * 128 * 2);
  ushort_t* WTo1  = (ushort_t*)alloc(128 * 128 * 2);
  ushort_t* WTp0  = (ushort_t*)alloc(128 * 128 * 2);
  ushort_t* WTp1  = (ushort_t*)alloc(128 * 128 * 2);
  int* elemb  = (int*)alloc(kN * 4);
  int* counts = (int*)alloc(kN * 4);
  int* cursor = (int*)alloc(kN * 4);
  int* offsb  = (int*)alloc((kN + 1) * 4);
  int* eidsb  = (int*)alloc((size_t)kE * 4);
  int* sendsb = (int*)alloc((size_t)kE * 4);
  if (off > ws_size) return;  // ~136 MB total

  // ---- prep ----
  zero_ints_kernel<<<kN/256, 256, 0, stream>>>(counts, cursor);
  elem_kernel<<<kN/256, 256, 0, stream>>>(node_attrs, elemb);
  init_feats_kernel<<<(kN*128)/256, 256, 0, stream>>>(W_embed, elemb, P0);
  count_kernel<<<kE/256, 256, 0, stream>>>(ei, counts);
  scan_kernel<<<1, 1024, 0, stream>>>(counts, offsb);
  fill_kernel<<<kE/256, 256, 0, stream>>>(ei, offsb, cursor, eidsb, sendsb);
  geom_kernel<<<kE/256, 256, 0, stream>>>(positions, shifts, ei, eidsb, sendsb, shcsr, rbcsr);
  transpose_w_kernel<<<64, 256, 0, stream>>>(W_up, WTu0);
  transpose_w_kernel<<<64, 256, 0, stream>>>(W_up + 16384, WTu1);
  transpose_w_kernel<<<64, 256, 0, stream>>>(W_out, WTo0);
  transpose_w_kernel<<<64, 256, 0, stream>>>(W_out + 16384, WTo1);
  transpose_w_kernel<<<64, 256, 0, stream>>>(W_plin, WTp0);
  transpose_w_kernel<<<64, 256, 0, stream>>>(W_plin + 16384, WTp1);
  transpose_r3_kernel<<<128, 256, 0, stream>>>(R_w3, R3T0);
  transpose_r3_kernel<<<128, 256, 0, stream>>>(R_w3 + 32768, R3T1);

  // ---- layer 0 (feats nonzero only at m=0) ----
  radial_kernel<<<kE/128, 256, 0, stream>>>(rbcsr, R_w1, R_w2, r2csr);
  mgemm_kernel<false,false,false><<<kN/128, 256, 0, stream>>>(
      P0, 2048, WTu0, P1, 2048, nullptr, nullptr, nullptr, nullptr);
  gather_kernel<<<dim3(kN/NPB, 2), 256, 0, stream>>>(offsb, sendsb, r2csr, shcsr, R3T0, P1, P2);
  mgemm_kernel<false,false,false><<<(kN*16)/128, 256, 0, stream>>>(
      P2, 128, WTo0, P0, 128, nullptr, nullptr, nullptr, nullptr);
  scale_kernel<<<(kN*128)/256, 256, 0, stream>>>(P0, elemb, w_prod, scaleb);
  mgemm_kernel<true,true,true><<<(kN*16)/128, 256, 0, stream>>>(
      P0, 128, WTp0, P2, 128, scaleb, P1, w_sc, elemb);
  readout_kernel<<<kN, 64, 0, stream>>>(P2, w_ro0, ro_w1, ro_w2, out, 0);

  // ---- layer 1 ----
  radial_kernel<<<kE/128, 256, 0, stream>>>(rbcsr, R_w1 + 512, R_w2 + 4096, r2csr);
  mgemm_kernel<false,false,false><<<(kN*16)/128, 256, 0, stream>>>(
      P2, 128, WTu1, P1, 128, nullptr, nullptr, nullptr, nullptr);
  gather_kernel<<<dim3(kN/NPB, 2), 256, 0, stream>>>(offsb, sendsb, r2csr, shcsr, R3T1, P1, P0);
  mgemm_kernel<false,false,false><<<(kN*16)/128, 256, 0, stream>>>(
      P0, 128, WTo1, P2, 128, nullptr, nullptr, nullptr, nullptr);
  scale_kernel<<<(kN*128)/256, 256, 0, stream>>>(P2, elemb, w_prod + 3840, scaleb);
  mgemm_kernel<true,true,false><<<(kN*16)/128, 256, 0, stream>>>(
      P2, 128, WTp1, P0, 128, scaleb, P1, w_sc + 1280, elemb);
  readout_kernel<<<kN, 64, 0, stream>>>(P0, w_ro0, ro_w1, ro_w2, out, 1);
}